// Round 2
// baseline (23414.111 us; speedup 1.0000x reference)
//
#include <hip/hip_runtime.h>
#include <cstdint>
#include <cstddef>

#define N_OBJ 2048
#define N_TOT 2064
#define NUM_CLASSES 151
#define EMBED 200
#define HID 512
#define OBJ_DIM 4096
#define POS 128
#define OBJ_IN 4424   // 4096+200+128
#define DEC_IN 4936   // 512+4424
#define EDGE_IN 4808  // 200+4096+512
#define G4 2048       // 4*HID
#define FLAG_STRIDE 16  // 64B between flags
#define SPIN_LIMIT 120000

// ----------------------------------------------------------------------------
// utility kernels
// ----------------------------------------------------------------------------
__global__ void init_flags_kernel(unsigned* flags, int n) {
  int i = blockIdx.x * blockDim.x + threadIdx.x;
  if (i < n) flags[i] = 0u;
}

__global__ void copy4_kernel(const float4* __restrict__ src, float4* __restrict__ dst, long n4) {
  long i = blockIdx.x * (long)blockDim.x + threadIdx.x;
  long stride = (long)gridDim.x * blockDim.x;
  for (; i < n4; i += stride) dst[i] = src[i];
}

// feats[r][0:4096] = x[r]
__global__ void copy_x_kernel(const float* __restrict__ x, float* __restrict__ feats) {
  long i = blockIdx.x * (long)blockDim.x + threadIdx.x; // over 2048*1024 float4
  if (i >= (long)N_OBJ * (OBJ_DIM / 4)) return;
  long r = i >> 10, c = i & 1023;
  reinterpret_cast<float4*>(feats + r * (long)OBJ_IN)[c] =
      reinterpret_cast<const float4*>(x + r * (long)OBJ_DIM)[c];
}

// feats[r][4096:4296] = obj_dists_in[r] @ embed1
__global__ void obj_embed_kernel(const float* __restrict__ dists,
                                 const float* __restrict__ embed1,
                                 float* __restrict__ feats) {
  int r = blockIdx.x;
  __shared__ float drow[NUM_CLASSES];
  for (int c = threadIdx.x; c < NUM_CLASSES; c += blockDim.x)
    drow[c] = dists[(size_t)r * NUM_CLASSES + c];
  __syncthreads();
  for (int j = threadIdx.x; j < EMBED; j += blockDim.x) {
    float s = 0.f;
    for (int k = 0; k < NUM_CLASSES; ++k)
      s = fmaf(drow[k], embed1[(size_t)k * EMBED + j], s);
    feats[(size_t)r * OBJ_IN + OBJ_DIM + j] = s;
  }
}

// feats[r][4296:4424] = relu(BN(box@W1+b1)@W2+b2)
__global__ void pos_kernel(const float* __restrict__ box,
                           const float* __restrict__ W1, const float* __restrict__ b1,
                           const float* __restrict__ gamma, const float* __restrict__ beta,
                           const float* __restrict__ mean, const float* __restrict__ var,
                           const float* __restrict__ W2, const float* __restrict__ b2,
                           float* __restrict__ feats) {
  int r = blockIdx.x;
  __shared__ float h[32];
  __shared__ float bx[9];
  if (threadIdx.x < 9) bx[threadIdx.x] = box[(size_t)r * 9 + threadIdx.x];
  __syncthreads();
  if (threadIdx.x < 32) {
    float s = b1[threadIdx.x];
    for (int k = 0; k < 9; ++k) s = fmaf(bx[k], W1[k * 32 + threadIdx.x], s);
    s = (s - mean[threadIdx.x]) * (1.f / sqrtf(var[threadIdx.x] + 1e-5f)) * gamma[threadIdx.x]
        + beta[threadIdx.x];
    h[threadIdx.x] = s;
  }
  __syncthreads();
  int j = threadIdx.x;
  if (j < POS) {
    float s = b2[j];
    for (int k = 0; k < 32; ++k) s = fmaf(h[k], W2[k * POS + j], s);
    feats[(size_t)r * OBJ_IN + OBJ_DIM + EMBED + j] = fmaxf(s, 0.f);
  }
}

// ----------------------------------------------------------------------------
// generic bounds-checked fp32 GEMM: C[M,N](ldc) = A[M,K](lda) @ B[K,N](ldb) (+bias | +=)
// tile 64x64, BK=16, 256 threads, 4x4 per thread
// ----------------------------------------------------------------------------
template <int ACC>
__global__ __launch_bounds__(256)
void gemm_kernel(const float* __restrict__ A, int lda,
                 const float* __restrict__ B, int ldb,
                 const float* __restrict__ bias,
                 float* __restrict__ C, int ldc,
                 int M, int N, int K) {
  __shared__ __align__(16) float As[16][68];
  __shared__ __align__(16) float Bs[16][64];
  const int row0 = blockIdx.y * 64;
  const int col0 = blockIdx.x * 64;
  const int tid = threadIdx.x;
  const int tx = tid & 15, ty = tid >> 4;
  float acc[4][4] = {};

  for (int k0 = 0; k0 < K; k0 += 16) {
#pragma unroll
    for (int l = 0; l < 4; ++l) {
      int idx = tid + l * 256;
      int m = idx >> 4, kk = idx & 15;
      int gm = row0 + m, gk = k0 + kk;
      As[kk][m] = (gm < M && gk < K) ? A[(size_t)gm * lda + gk] : 0.f;
    }
#pragma unroll
    for (int l = 0; l < 4; ++l) {
      int idx = tid + l * 256;
      int kk = idx >> 6, n = idx & 63;
      int gk = k0 + kk, gn = col0 + n;
      Bs[kk][n] = (gk < K && gn < N) ? B[(size_t)gk * ldb + gn] : 0.f;
    }
    __syncthreads();
#pragma unroll
    for (int kk = 0; kk < 16; ++kk) {
      float4 a = *reinterpret_cast<const float4*>(&As[kk][ty * 4]);
      float4 b = *reinterpret_cast<const float4*>(&Bs[kk][tx * 4]);
      acc[0][0] = fmaf(a.x, b.x, acc[0][0]); acc[0][1] = fmaf(a.x, b.y, acc[0][1]);
      acc[0][2] = fmaf(a.x, b.z, acc[0][2]); acc[0][3] = fmaf(a.x, b.w, acc[0][3]);
      acc[1][0] = fmaf(a.y, b.x, acc[1][0]); acc[1][1] = fmaf(a.y, b.y, acc[1][1]);
      acc[1][2] = fmaf(a.y, b.z, acc[1][2]); acc[1][3] = fmaf(a.y, b.w, acc[1][3]);
      acc[2][0] = fmaf(a.z, b.x, acc[2][0]); acc[2][1] = fmaf(a.z, b.y, acc[2][1]);
      acc[2][2] = fmaf(a.z, b.z, acc[2][2]); acc[2][3] = fmaf(a.z, b.w, acc[2][3]);
      acc[3][0] = fmaf(a.w, b.x, acc[3][0]); acc[3][1] = fmaf(a.w, b.y, acc[3][1]);
      acc[3][2] = fmaf(a.w, b.z, acc[3][2]); acc[3][3] = fmaf(a.w, b.w, acc[3][3]);
    }
    __syncthreads();
  }
#pragma unroll
  for (int i = 0; i < 4; ++i) {
    int gm = row0 + ty * 4 + i;
    if (gm >= M) continue;
#pragma unroll
    for (int j = 0; j < 4; ++j) {
      int gn = col0 + tx * 4 + j;
      if (gn >= N) continue;
      size_t o = (size_t)gm * ldc + gn;
      if (ACC) C[o] += acc[i][j];
      else C[o] = acc[i][j] + (bias ? bias[gn] : 0.f);
    }
  }
}

// ----------------------------------------------------------------------------
// persistent LSTM scan: 32 WGs x 256 threads. WG wg owns h-dims [16*wg, 16*wg+16).
// Wh columns for those dims (64 cols x 512) live in registers (128 floats/thread).
// Cross-WG sync per step: per-block flag array (no RMW contention), release-store
// by producer, acquire-poll (bounded) by one wave. Agent-scope atomics throughout
// so per-XCD L2 non-coherence cannot serve stale h.
// ----------------------------------------------------------------------------
__global__ __launch_bounds__(256, 1)
void lstm_scan_kernel(const float* __restrict__ pre,  // T x 2048
                      const float* __restrict__ Wh,   // 512 x 2048
                      float* __restrict__ hs,         // T x 512
                      float* hg,                      // 2*512 exchange buffer
                      unsigned* flags,                // 32 flags, FLAG_STRIDE apart, zeroed
                      int T) {
  __shared__ float hl[HID];
  __shared__ float red[4][64];
  __shared__ float gate[4][16];
  const int tid = threadIdx.x;
  const int wg = blockIdx.x;      // 0..31
  const int d0 = wg * 16;
  const int c = tid & 63;         // col within this WG's 64-col slice
  const int p = tid >> 6;         // k-part 0..3 (each covers 128 of 512)
  const int g = c >> 4;           // gate 0..3 (i,f,g,o)
  const int j = c & 15;
  const int colw = g * HID + d0 + j;

  // preload this thread's 128 Wh weights into registers
  float w[128];
  {
    const float* base = Wh + (size_t)(p * 128) * G4 + colw;
#pragma unroll
    for (int q = 0; q < 128; ++q) w[q] = base[(size_t)q * G4];
  }
  hl[tid] = 0.f;
  hl[tid + 256] = 0.f;
  float creg = 0.f;
  bool dead = false;              // wave-0 failsafe latch (uniform across lanes)
  __syncthreads();

  for (int s = 0; s < T; ++s) {
    // prefetch this step's pre-activation slice (overlaps with the dot product)
    float prev = 0.f;
    if (tid < 64)
      prev = pre[(size_t)s * G4 + (tid >> 4) * HID + d0 + (tid & 15)];

    // partial dot: w (regs) . h (LDS, broadcast reads)
    float s0 = 0.f, s1 = 0.f, s2 = 0.f, s3 = 0.f;
    const float* hp = &hl[p * 128];
#pragma unroll
    for (int q4 = 0; q4 < 32; ++q4) {
      float4 h4 = reinterpret_cast<const float4*>(hp)[q4];
      s0 = fmaf(w[4 * q4 + 0], h4.x, s0);
      s1 = fmaf(w[4 * q4 + 1], h4.y, s1);
      s2 = fmaf(w[4 * q4 + 2], h4.z, s2);
      s3 = fmaf(w[4 * q4 + 3], h4.w, s3);
    }
    red[p][c] = (s0 + s1) + (s2 + s3);
    __syncthreads();

    if (tid < 64) {
      float v = red[0][tid] + red[1][tid] + red[2][tid] + red[3][tid] + prev;
      gate[tid >> 4][tid & 15] = v;
    }
    __syncthreads();

    if (tid < 16) {
      float vi = gate[0][tid], vf = gate[1][tid], vg = gate[2][tid], vo = gate[3][tid];
      float si = 1.f / (1.f + expf(-vi));
      float sf = 1.f / (1.f + expf(-vf));
      float so = 1.f / (1.f + expf(-vo));
      creg = sf * creg + si * tanhf(vg);
      float h = so * tanhf(creg);
      hs[(size_t)s * HID + d0 + tid] = h;
      __hip_atomic_store(&hg[(s & 1) * HID + d0 + tid], h,
                         __ATOMIC_RELAXED, __HIP_MEMORY_SCOPE_AGENT);
    }
    __syncthreads();  // all waves reach here; each wave's stores drained (vmcnt) first

    if (tid == 0)     // publish: this block finished step s
      __hip_atomic_store(&flags[wg * FLAG_STRIDE], (unsigned)(s + 1),
                         __ATOMIC_RELEASE, __HIP_MEMORY_SCOPE_AGENT);

    // wave 0 polls all 32 flags (one 32-lane load per poll; bounded)
    if (tid < 64 && !dead) {
      int tries = 0;
      for (;;) {
        unsigned f = (tid < 32)
            ? __hip_atomic_load(&flags[tid * FLAG_STRIDE], __ATOMIC_ACQUIRE,
                                __HIP_MEMORY_SCOPE_AGENT)
            : 0xFFFFFFFFu;
        if (__all((int)(f >= (unsigned)(s + 1)))) break;
        if (++tries > SPIN_LIMIT) { dead = true; break; }  // failsafe: degrade, don't hang
        __builtin_amdgcn_s_sleep(4);
      }
    }
    __syncthreads();

    // reload the full h vector for the next step
    const int b = (s & 1) * HID;
    hl[tid] = __hip_atomic_load(&hg[b + tid], __ATOMIC_RELAXED, __HIP_MEMORY_SCOPE_AGENT);
    hl[tid + 256] =
        __hip_atomic_load(&hg[b + tid + 256], __ATOMIC_RELAXED, __HIP_MEMORY_SCOPE_AGENT);
    __syncthreads();
  }
}

// ----------------------------------------------------------------------------
// argmax over 151 logits per row (first-occurrence semantics), one wave per row
// ----------------------------------------------------------------------------
__global__ void argmax_kernel(const float* __restrict__ dists, int* __restrict__ pred_i,
                              float* __restrict__ pred_f) {
  int r = blockIdx.x;
  int lane = threadIdx.x;
  float bv = -3.4e38f;
  int bi = NUM_CLASSES;
  for (int cc = lane; cc < NUM_CLASSES; cc += 64) {
    float v = dists[(size_t)r * NUM_CLASSES + cc];
    if (v > bv) { bv = v; bi = cc; }  // cc strictly increasing per lane -> first max kept
  }
  for (int off = 32; off; off >>= 1) {
    float ov = __shfl_xor(bv, off);
    int oi = __shfl_xor(bi, off);
    if (ov > bv || (ov == bv && oi < bi)) { bv = ov; bi = oi; }
  }
  if (lane == 0) {
    pred_i[r] = bi;
    pred_f[r] = (float)bi;
  }
}

// edge_feats[r] = [embed2[pred[r]] | x[r] | enc[r]] (r<2048) else virtual_edge[r-2048]
__global__ void build_edge_kernel(const float* __restrict__ embed2, const int* __restrict__ pred,
                                  const float* __restrict__ x, const float* __restrict__ enc,
                                  const float* __restrict__ vedge, float* __restrict__ out) {
  int r = blockIdx.x;
  float* dst = out + (size_t)r * EDGE_IN;
  if (r >= N_OBJ) {
    const float* src = vedge + (size_t)(r - N_OBJ) * EDGE_IN;
    for (int cc = threadIdx.x; cc < EDGE_IN; cc += blockDim.x) dst[cc] = src[cc];
  } else {
    const float* e = embed2 + (size_t)pred[r] * EMBED;
    for (int cc = threadIdx.x; cc < EMBED; cc += blockDim.x) dst[cc] = e[cc];
    const float* xr = x + (size_t)r * OBJ_DIM;
    for (int cc = threadIdx.x; cc < OBJ_DIM; cc += blockDim.x) dst[EMBED + cc] = xr[cc];
    const float* er = enc + (size_t)r * HID;
    for (int cc = threadIdx.x; cc < HID; cc += blockDim.x) dst[EMBED + OBJ_DIM + cc] = er[cc];
  }
}

// ----------------------------------------------------------------------------
extern "C" void kernel_launch(void* const* d_in, const int* in_sizes, int n_in,
                              void* d_out, int out_size, void* d_ws, size_t ws_size,
                              hipStream_t stream) {
  const float* x        = (const float*)d_in[0];
  const float* odists   = (const float*)d_in[1];
  const float* box      = (const float*)d_in[2];
  const float* vobj     = (const float*)d_in[3];
  const float* vedge    = (const float*)d_in[4];
  const float* embed1   = (const float*)d_in[5];
  const float* embed2   = (const float*)d_in[6];
  const float* pos_W1   = (const float*)d_in[7];
  const float* pos_b1   = (const float*)d_in[8];
  const float* bn_gamma = (const float*)d_in[9];
  const float* bn_beta  = (const float*)d_in[10];
  const float* bn_mean  = (const float*)d_in[11];
  const float* bn_var   = (const float*)d_in[12];
  const float* pos_W2   = (const float*)d_in[13];
  const float* pos_b2   = (const float*)d_in[14];
  const float* obj_Wi   = (const float*)d_in[15];
  const float* obj_Wh   = (const float*)d_in[16];
  const float* obj_b    = (const float*)d_in[17];
  const float* dec_Wi   = (const float*)d_in[18];
  const float* dec_Wh   = (const float*)d_in[19];
  const float* dec_b    = (const float*)d_in[20];
  const float* out_W    = (const float*)d_in[21];
  const float* out_b    = (const float*)d_in[22];
  const float* edge_Wi  = (const float*)d_in[23];
  const float* edge_Wh  = (const float*)d_in[24];
  const float* edge_b   = (const float*)d_in[25];

  float* out = (float*)d_out;

  // workspace layout (floats) — edgeh aliases dech (logits GEMM completes first)
  float* bigA  = (float*)d_ws;                          // 2064x4808 max
  float* pre   = bigA + (size_t)N_TOT * EDGE_IN;        // 2064x2048
  float* enc   = pre + (size_t)N_TOT * G4;              // 2064x512
  float* dech  = enc + (size_t)N_TOT * HID;             // 2064x512 (also edgeh)
  float* hg    = dech + (size_t)N_TOT * HID;            // 2x512
  int* pred_i  = (int*)(hg + 2 * HID);                  // 2048
  unsigned* flags = (unsigned*)(pred_i + N_OBJ);        // 3*32*FLAG_STRIDE

  const size_t need_bytes =
      ((size_t)N_TOT * EDGE_IN + (size_t)N_TOT * G4 + 2 * (size_t)N_TOT * HID + 2 * HID) * 4 +
      (size_t)N_OBJ * 4 + 3 * 32 * FLAG_STRIDE * 4 + 256;
  if (ws_size < need_bytes) return;  // insufficient scratch: fail loudly, don't corrupt

  const size_t OUT_PRED = (size_t)N_OBJ * NUM_CLASSES;  // 309248
  const size_t OUT_EDGE = OUT_PRED + N_OBJ;             // 311296

  init_flags_kernel<<<(3 * 32 * FLAG_STRIDE + 255) / 256, 256, 0, stream>>>(
      flags, 3 * 32 * FLAG_STRIDE);

  // build feats
  copy_x_kernel<<<(N_OBJ * (OBJ_DIM / 4) + 255) / 256, 256, 0, stream>>>(x, bigA);
  {
    long n4 = (long)16 * OBJ_IN / 4;
    copy4_kernel<<<(unsigned)((n4 + 255) / 256), 256, 0, stream>>>(
        (const float4*)vobj, (float4*)(bigA + (size_t)N_OBJ * OBJ_IN), n4);
  }
  obj_embed_kernel<<<N_OBJ, 256, 0, stream>>>(odists, embed1, bigA);
  pos_kernel<<<N_OBJ, 128, 0, stream>>>(box, pos_W1, pos_b1, bn_gamma, bn_beta, bn_mean,
                                        bn_var, pos_W2, pos_b2, bigA);

  // encoder LSTM
  gemm_kernel<0><<<dim3(32, 33), 256, 0, stream>>>(bigA, OBJ_IN, obj_Wi, G4, obj_b,
                                                   pre, G4, N_TOT, G4, OBJ_IN);
  lstm_scan_kernel<<<32, 256, 0, stream>>>(pre, obj_Wh, enc, hg, flags + 0 * 32 * FLAG_STRIDE,
                                           N_TOT);

  // decoder LSTM (input = [feats | enc], done as two GEMMs)
  gemm_kernel<0><<<dim3(32, 33), 256, 0, stream>>>(bigA, OBJ_IN, dec_Wi, G4, dec_b,
                                                   pre, G4, N_TOT, G4, OBJ_IN);
  gemm_kernel<1><<<dim3(32, 33), 256, 0, stream>>>(enc, HID, dec_Wi + (size_t)OBJ_IN * G4, G4,
                                                   nullptr, pre, G4, N_TOT, G4, HID);
  lstm_scan_kernel<<<32, 256, 0, stream>>>(pre, dec_Wh, dech, hg, flags + 1 * 32 * FLAG_STRIDE,
                                           N_TOT);

  // logits (rows 0..2047 only) straight into d_out, then argmax
  gemm_kernel<0><<<dim3(3, 32), 256, 0, stream>>>(dech, HID, out_W, NUM_CLASSES, out_b,
                                                  out, NUM_CLASSES, N_OBJ, NUM_CLASSES, HID);
  argmax_kernel<<<N_OBJ, 64, 0, stream>>>(out, pred_i, out + OUT_PRED);

  // edge LSTM (edgeh aliases dech — safe: logits GEMM already consumed dech)
  build_edge_kernel<<<N_TOT, 256, 0, stream>>>(embed2, pred_i, x, enc, vedge, bigA);
  gemm_kernel<0><<<dim3(32, 33), 256, 0, stream>>>(bigA, EDGE_IN, edge_Wi, G4, edge_b,
                                                   pre, G4, N_TOT, G4, EDGE_IN);
  lstm_scan_kernel<<<32, 256, 0, stream>>>(pre, edge_Wh, dech, hg, flags + 2 * 32 * FLAG_STRIDE,
                                           N_TOT);

  // edge_ctx = edgeh[:2048] -> d_out
  copy4_kernel<<<1024, 256, 0, stream>>>((const float4*)dech, (float4*)(out + OUT_EDGE),
                                         (long)N_OBJ * HID / 4);
}